// Round 6
// baseline (211.977 us; speedup 1.0000x reference)
//
#include <hip/hip_runtime.h>
#include <hip/hip_bf16.h>
#include <stdint.h>

#define N_BATCH 4096
#define D_DIM   1024
#define M_ROWS  8192                     // 2N
#define TINV    2.0f                     // 1/temperature
#define EXP_SCALE 2.8853900817779268f    // log2(e)/t  (t=0.5)
#define LN2 0.6931471805599453f
#define NBLK 1056                        // sum_{by<64} (32 - (by>>1))
#define NKT 32                           // K steps of 32 (K=1024)

typedef __bf16 bf16x8 __attribute__((ext_vector_type(8)));
typedef float  f32x4  __attribute__((ext_vector_type(4)));

__device__ __forceinline__ void load_lds16(const __bf16* g, __bf16* l) {
    __builtin_amdgcn_global_load_lds(
        (const __attribute__((address_space(1))) void*)g,
        (__attribute__((address_space(3))) void*)l, 16, 0, 0);
}

// ---- kernel 1: fused L2-normalize (bf16 Z out) + exact fp32 positives ----
__global__ __launch_bounds__(256) void norm_pos_kernel(
    const float* __restrict__ emb_i, const float* __restrict__ emb_j,
    __bf16* __restrict__ zb, float* __restrict__ pos, float* __restrict__ denom)
{
    int i = blockIdx.x;
    int t = threadIdx.x;
    float4 va = ((const float4*)(emb_i + (size_t)i * D_DIM))[t];
    float4 vb = ((const float4*)(emb_j + (size_t)i * D_DIM))[t];
    float ssa = va.x*va.x + va.y*va.y + va.z*va.z + va.w*va.w;
    float ssb = vb.x*vb.x + vb.y*vb.y + vb.z*vb.z + vb.w*vb.w;
    float dot = va.x*vb.x + va.y*vb.y + va.z*vb.z + va.w*vb.w;
    #pragma unroll
    for (int m = 1; m < 64; m <<= 1) {
        ssa += __shfl_xor(ssa, m, 64);
        ssb += __shfl_xor(ssb, m, 64);
        dot += __shfl_xor(dot, m, 64);
    }
    __shared__ float ra[4], rb[4], rd[4];
    int wv = t >> 6;
    if ((t & 63) == 0) { ra[wv] = ssa; rb[wv] = ssb; rd[wv] = dot; }
    __syncthreads();
    float SSA = ra[0] + ra[1] + ra[2] + ra[3];
    float SSB = rb[0] + rb[1] + rb[2] + rb[3];
    float na = fmaxf(sqrtf(SSA), 1e-12f);
    float nb = fmaxf(sqrtf(SSB), 1e-12f);
    float sa = 1.0f / na, sb = 1.0f / nb;
    union { __bf16 h[4]; uint2 u; } cv;
    cv.h[0] = (__bf16)(va.x * sa); cv.h[1] = (__bf16)(va.y * sa);
    cv.h[2] = (__bf16)(va.z * sa); cv.h[3] = (__bf16)(va.w * sa);
    *(uint2*)(zb + (size_t)i * D_DIM + t * 4) = cv.u;
    cv.h[0] = (__bf16)(vb.x * sb); cv.h[1] = (__bf16)(vb.y * sb);
    cv.h[2] = (__bf16)(vb.z * sb); cv.h[3] = (__bf16)(vb.w * sb);
    *(uint2*)(zb + (size_t)(i + N_BATCH) * D_DIM + t * 4) = cv.u;
    if (t == 0) {
        float DOT = rd[0] + rd[1] + rd[2] + rd[3];
        pos[i] = DOT / (na * nb);
        denom[i] = 0.0f;
        denom[i + N_BATCH] = 0.0f;
    }
}

// ---- kernel 2: fused sim = Z Z^T -> exp -> masked row/col sums -----------
// Round-5 proven schedule (3-ring, counted vmcnt, bare s_barrier, both-sides
// XOR swizzle) with NEW GEOMETRY to cut LDS traffic per FLOP:
//   128x256 block tile, 4 waves of 128x64 each (12 ds_read per 32 MFMA =
//   0.375 vs 0.5 before). Per block-K-step: 48 reads + 24 KB DMA writes =
//   72 KB LDS per 2.1 MFLOP (x0.75 of round-5). 3-ring = 72 KiB -> 2 blk/CU.
// Cover: block (by, bc) = rows [128by,128by+128) x cols [256bc,256bc+256),
//   valid iff bc >= by>>1. Every cell (r,c), c>r lies in exactly one block;
//   the per-element c>r predicate masks diagonal-straddling tiles.
// vmcnt ledger: 6 loads/thread/step (A:2, B:4); stage kt+2 during kt;
//   boundary vmcnt(6) = kt+1 landed, kt+2 in flight. vmcnt(0) only at tail.
__global__ __launch_bounds__(256, 2) void simexp_kernel(
    const __bf16* __restrict__ Z, float* __restrict__ denom)
{
    // bijective XCD swizzle (1056 = 8 x 132)
    int orig = blockIdx.x;
    int idx  = (orig & 7) * (NBLK / 8) + (orig >> 3);
    // decode: by-major; counts 32 - (by>>1) per by
    int by = 0, rem = idx, cnt = 32;
    while (rem >= cnt) { rem -= cnt; ++by; cnt = 32 - (by >> 1); }
    int bc = (by >> 1) + rem;

    int tile_m = by * 128, tile_n = bc * 256;

    // ring: A[3][128*32], B[3][256*32] bf16 -> 24 KiB + 48 KiB = 72 KiB
    __shared__ __align__(16) __bf16 shA[3][128 * 32];
    __shared__ __align__(16) __bf16 shB[3][256 * 32];

    int t    = threadIdx.x;          // 0..255
    int wv   = t >> 6;               // 0..3
    int lane = t & 63;
    int wave_n = wv * 64;            // wave-tile: 128 rows x 64 cols
    int quad = lane >> 4;
    int l15  = lane & 15;

    // staging: per 64-row group, thread t fills LDS slot (row=t>>2, oct=t&3);
    // that slot holds global octet (t&3)^((t>>3)&3)  (both-sides swizzle,
    // (row>>1)&3 == (t>>3)&3 since row = t>>2)
    int srow = t >> 2;
    int soct = ((t & 3) ^ ((t >> 3) & 3)) * 8;
    const __bf16* gA = Z + (size_t)(tile_m + srow) * D_DIM + soct;
    const __bf16* gB = Z + (size_t)(tile_n + srow) * D_DIM + soct;

    // ds_read swizzled column: oct = quad ^ ((row>>1)&3); row = f*16+l15 so
    // (row>>1)&3 == (l15>>1)&3  (f*16 contributes 0 mod 4 after >>1)
    int swz = (quad ^ ((l15 >> 1) & 3)) * 8;

    f32x4 acc[8][4] = {};

    // prologue: stage K-steps 0 and 1 (12 loads/thread); step 0 landed
    #pragma unroll
    for (int pt = 0; pt < 2; ++pt) {
        #pragma unroll
        for (int g = 0; g < 2; ++g)
            load_lds16(gA + pt * 32 + (size_t)g * 64 * D_DIM,
                       &shA[pt][g * 2048 + t * 8]);
        #pragma unroll
        for (int g = 0; g < 4; ++g)
            load_lds16(gB + pt * 32 + (size_t)g * 64 * D_DIM,
                       &shB[pt][g * 2048 + t * 8]);
    }
    asm volatile("s_waitcnt vmcnt(6)" ::: "memory");
    __builtin_amdgcn_sched_barrier(0);
    __builtin_amdgcn_s_barrier();

    int cur = 0;
    for (int kt = 0; kt < NKT; ++kt) {
        int wrt = cur + 2; if (wrt >= 3) wrt -= 3;
        if (kt < NKT - 2) {              // stage K-step kt+2 into ring slot
            int k0 = (kt + 2) * 32;
            #pragma unroll
            for (int g = 0; g < 2; ++g)
                load_lds16(gA + k0 + (size_t)g * 64 * D_DIM,
                           &shA[wrt][g * 2048 + t * 8]);
            #pragma unroll
            for (int g = 0; g < 4; ++g)
                load_lds16(gB + k0 + (size_t)g * 64 * D_DIM,
                           &shB[wrt][g * 2048 + t * 8]);
        }
        const __bf16* sA = &shA[cur][0];
        const __bf16* sB = &shB[cur][0];
        bf16x8 bf[4], af[8];
        #pragma unroll
        for (int n = 0; n < 4; ++n)
            bf[n] = *(const bf16x8*)&sB[(wave_n + n * 16 + l15) * 32 + swz];
        #pragma unroll
        for (int f = 0; f < 8; ++f)
            af[f] = *(const bf16x8*)&sA[(f * 16 + l15) * 32 + swz];

        __builtin_amdgcn_s_setprio(1);
        #pragma unroll
        for (int f = 0; f < 8; ++f)
            #pragma unroll
            for (int n = 0; n < 4; ++n)
                acc[f][n] = __builtin_amdgcn_mfma_f32_16x16x32_bf16(
                    af[f], bf[n], acc[f][n], 0, 0, 0);
        __builtin_amdgcn_s_setprio(0);

        // boundary: kt+1 must be landed; kt+2's 6 loads may stay in flight
        if (kt < NKT - 2) asm volatile("s_waitcnt vmcnt(6)" ::: "memory");
        else              asm volatile("s_waitcnt vmcnt(0)" ::: "memory");
        __builtin_amdgcn_sched_barrier(0);
        __builtin_amdgcn_s_barrier();
        cur = (cur == 2) ? 0 : cur + 1;
    }

    // epilogue: e = exp2(sim*log2(e)/t) only where c>r; row + col reductions
    int rbase = tile_m + quad * 4;
    int cbase = tile_n + wave_n + l15;
    float colacc[4] = {0.f, 0.f, 0.f, 0.f};
    #pragma unroll
    for (int f = 0; f < 8; ++f) {
        #pragma unroll
        for (int r = 0; r < 4; ++r) {
            int rg = rbase + f * 16 + r;
            float rowacc = 0.f;
            #pragma unroll
            for (int n = 0; n < 4; ++n) {
                int cg = cbase + n * 16;
                float e = (cg > rg)
                    ? __builtin_amdgcn_exp2f(acc[f][n][r] * EXP_SCALE)
                    : 0.f;
                rowacc += e;
                colacc[n] += e;
            }
            rowacc += __shfl_xor(rowacc, 1, 64);
            rowacc += __shfl_xor(rowacc, 2, 64);
            rowacc += __shfl_xor(rowacc, 4, 64);
            rowacc += __shfl_xor(rowacc, 8, 64);
            if (l15 == 0) atomicAdd(&denom[rg], rowacc);
        }
    }
    #pragma unroll
    for (int n = 0; n < 4; ++n) {
        float s = colacc[n];
        s += __shfl_xor(s, 16, 64);
        s += __shfl_xor(s, 32, 64);
        if (quad == 0) atomicAdd(&denom[cbase + n * 16], s);
    }
}

// ---- kernel 3: loss = [sum log(denom) - (2/t) sum pos] / 2N --------------
// 1024 threads (16 waves, 1 block) -- 4x the load ILP of the old 256-thread
// version; single-block stays deterministic.
__global__ __launch_bounds__(1024) void finalize_kernel(
    const float* __restrict__ denom, const float* __restrict__ pos,
    float* __restrict__ out)
{
    float a1 = 0.f, a2 = 0.f;
    for (int r = threadIdx.x; r < M_ROWS; r += 1024)
        a1 += __builtin_amdgcn_logf(denom[r]) * LN2;   // v_log_f32 is log2
    for (int i = threadIdx.x; i < N_BATCH; i += 1024)
        a2 += pos[i];
    #pragma unroll
    for (int m = 1; m < 64; m <<= 1) {
        a1 += __shfl_xor(a1, m, 64);
        a2 += __shfl_xor(a2, m, 64);
    }
    __shared__ float r1[16], r2[16];
    int wv = threadIdx.x >> 6;
    if ((threadIdx.x & 63) == 0) { r1[wv] = a1; r2[wv] = a2; }
    __syncthreads();
    if (threadIdx.x == 0) {
        float s1 = 0.f, s2 = 0.f;
        #pragma unroll
        for (int w = 0; w < 16; ++w) { s1 += r1[w]; s2 += r2[w]; }
        out[0] = (s1 - 2.0f * TINV * s2) / (float)M_ROWS;
    }
}

extern "C" void kernel_launch(void* const* d_in, const int* in_sizes, int n_in,
                              void* d_out, int out_size, void* d_ws, size_t ws_size,
                              hipStream_t stream)
{
    const float* emb_i = (const float*)d_in[0];
    const float* emb_j = (const float*)d_in[1];
    float* out = (float*)d_out;

    char*   ws    = (char*)d_ws;
    __bf16* zb    = (__bf16*)ws;                                   // 16 MB
    float*  denom = (float*)(ws + (size_t)M_ROWS * D_DIM * 2);     // 32 KB
    float*  pos   = denom + M_ROWS;                                // 16 KB

    hipLaunchKernelGGL(norm_pos_kernel, dim3(N_BATCH), dim3(256), 0, stream,
                       emb_i, emb_j, zb, pos, denom);
    hipLaunchKernelGGL(simexp_kernel, dim3(NBLK), dim3(256), 0, stream,
                       zb, denom);
    hipLaunchKernelGGL(finalize_kernel, dim3(1), dim3(1024), 0, stream,
                       denom, pos, out);
}

// Round 7
// 172.357 us; speedup vs baseline: 1.2299x; 1.2299x over previous
//
#include <hip/hip_runtime.h>
#include <hip/hip_bf16.h>
#include <stdint.h>

#define N_BATCH 4096
#define D_DIM   1024
#define M_ROWS  8192                     // 2N
#define TINV    2.0f                     // 1/temperature
#define EXP_SCALE 2.8853900817779268f    // log2(e)/t  (t=0.5)
#define LN2 0.6931471805599453f
#define NB 64                            // 8192/128 tiles per dim
#define NTRI 2080                        // NB*(NB+1)/2 upper-tri tiles
#define NKT 32                           // K steps of 32 (K=1024)

typedef __bf16 bf16x8 __attribute__((ext_vector_type(8)));
typedef float  f32x4  __attribute__((ext_vector_type(4)));

__device__ __forceinline__ void load_lds16(const __bf16* g, __bf16* l) {
    __builtin_amdgcn_global_load_lds(
        (const __attribute__((address_space(1))) void*)g,
        (__attribute__((address_space(3))) void*)l, 16, 0, 0);
}

// ---- kernel 1: fused L2-normalize (bf16 Z out) + exact fp32 positives ----
// ONE WAVE per row-pair (was: one 256-thr block + LDS + 2-stage reduce).
// Lane l holds 4 float4 per side (stride-64 float4 -> fully coalesced 1KB
// per wave per iter); 3 wave-local shfl_xor chains; no LDS, no syncthreads.
__global__ __launch_bounds__(256) void norm_pos_kernel(
    const float* __restrict__ emb_i, const float* __restrict__ emb_j,
    __bf16* __restrict__ zb, float* __restrict__ pos, float* __restrict__ denom)
{
    int w    = threadIdx.x >> 6;                 // wave 0..3
    int lane = threadIdx.x & 63;
    int row  = blockIdx.x * 4 + w;               // 0..4095 (grid = 1024)
    const float4* Ai = (const float4*)(emb_i + (size_t)row * D_DIM);
    const float4* Bj = (const float4*)(emb_j + (size_t)row * D_DIM);
    float4 a[4], b[4];
    #pragma unroll
    for (int j = 0; j < 4; ++j) {
        a[j] = Ai[lane + 64 * j];
        b[j] = Bj[lane + 64 * j];
    }
    float ssa = 0.f, ssb = 0.f, dot = 0.f;
    #pragma unroll
    for (int j = 0; j < 4; ++j) {
        ssa += a[j].x*a[j].x + a[j].y*a[j].y + a[j].z*a[j].z + a[j].w*a[j].w;
        ssb += b[j].x*b[j].x + b[j].y*b[j].y + b[j].z*b[j].z + b[j].w*b[j].w;
        dot += a[j].x*b[j].x + a[j].y*b[j].y + a[j].z*b[j].z + a[j].w*b[j].w;
    }
    #pragma unroll
    for (int m = 1; m < 64; m <<= 1) {
        ssa += __shfl_xor(ssa, m, 64);
        ssb += __shfl_xor(ssb, m, 64);
        dot += __shfl_xor(dot, m, 64);
    }
    float na = fmaxf(sqrtf(ssa), 1e-12f);
    float nb = fmaxf(sqrtf(ssb), 1e-12f);
    float sa = 1.0f / na, sb = 1.0f / nb;
    #pragma unroll
    for (int j = 0; j < 4; ++j) {
        union { __bf16 h[4]; uint2 u; } cv;
        cv.h[0] = (__bf16)(a[j].x * sa); cv.h[1] = (__bf16)(a[j].y * sa);
        cv.h[2] = (__bf16)(a[j].z * sa); cv.h[3] = (__bf16)(a[j].w * sa);
        *(uint2*)(zb + (size_t)row * D_DIM + (lane + 64 * j) * 4) = cv.u;
        cv.h[0] = (__bf16)(b[j].x * sb); cv.h[1] = (__bf16)(b[j].y * sb);
        cv.h[2] = (__bf16)(b[j].z * sb); cv.h[3] = (__bf16)(b[j].w * sb);
        *(uint2*)(zb + (size_t)(row + N_BATCH) * D_DIM + (lane + 64 * j) * 4) = cv.u;
    }
    if (lane == 0) {
        pos[row] = dot / (na * nb);
        denom[row] = 0.0f;
        denom[row + N_BATCH] = 0.0f;
    }
}

// ---- kernel 2: fused sim = Z Z^T -> exp -> masked row/col sums -----------
// BYTE-IDENTICAL to round-5 proven best (103.8 us, MfmaUtil 28.7, 0 conflicts):
// 128x128 tile, BK=32, 256 thr, 3-buffer LDS ring (48 KiB -> 3 blk/CU),
// counted vmcnt(4) + bare s_barrier (T4), both-sides XOR swizzle,
// triangular grid + bijective XCD swizzle.
__global__ __launch_bounds__(256, 3) void simexp_kernel(
    const __bf16* __restrict__ Z, float* __restrict__ denom)
{
    // XCD swizzle then decode linear idx -> (by, bx) with bx >= by
    int orig = blockIdx.x;
    int idx  = (orig & 7) * (NTRI / 8) + (orig >> 3);
    int by = (int)((129.0f - sqrtf(16641.0f - 8.0f * (float)idx)) * 0.5f);
    if (by > NB - 1) by = NB - 1;
    if (by < 0) by = 0;
    int off = (by * (129 - by)) >> 1;           // tiles before row `by`
    while (off > idx)                 { --by; off = (by * (129 - by)) >> 1; }
    while (off + (NB - by) <= idx)    { off += NB - by; ++by; }
    int bx = by + (idx - off);

    int tile_m = by * 128, tile_n = bx * 128;

    // [ring 0..2][A=0/B=1][128*32 bf16]  -> 48 KiB total
    __shared__ __align__(16) __bf16 sh[3][2][128 * 32];

    int t    = threadIdx.x;
    int wv   = t >> 6;
    int lane = t & 63;
    int wave_m = (wv >> 1) * 64;
    int wave_n = (wv & 1) * 64;
    int quad = lane >> 4;
    int l15  = lane & 15;

    // staging: thread t fills LDS slot (row=t>>2, slot=t&3); that slot must
    // hold global octet  o = (t&3) ^ ((t>>3)&3)   (both-sides swizzle)
    int srow = t >> 2;
    int soct = ((t & 3) ^ ((t >> 3) & 3)) * 8;
    const __bf16* gA = Z + (size_t)(tile_m + srow) * D_DIM + soct;
    const __bf16* gB = Z + (size_t)(tile_n + srow) * D_DIM + soct;

    // ds_read swizzled column: oct = quad ^ ((row>>1)&3)
    int swz = (quad ^ ((l15 >> 1) & 3)) * 8;

    f32x4 acc[4][4] = {};

    // prologue: stage K-steps 0 and 1 (8 loads/thread); step 0 landed
    #pragma unroll
    for (int pt = 0; pt < 2; ++pt) {
        load_lds16(gA + pt * 32,               &sh[pt][0][wv * 512]);
        load_lds16(gA + pt * 32 + 64 * D_DIM,  &sh[pt][0][2048 + wv * 512]);
        load_lds16(gB + pt * 32,               &sh[pt][1][wv * 512]);
        load_lds16(gB + pt * 32 + 64 * D_DIM,  &sh[pt][1][2048 + wv * 512]);
    }
    asm volatile("s_waitcnt vmcnt(4)" ::: "memory");
    __builtin_amdgcn_sched_barrier(0);
    __builtin_amdgcn_s_barrier();

    int cur = 0;
    for (int kt = 0; kt < NKT; ++kt) {
        int wrt = cur + 2; if (wrt >= 3) wrt -= 3;
        if (kt < NKT - 2) {              // stage K-step kt+2 into ring slot
            int k0 = (kt + 2) * 32;
            load_lds16(gA + k0,              &sh[wrt][0][wv * 512]);
            load_lds16(gA + k0 + 64 * D_DIM, &sh[wrt][0][2048 + wv * 512]);
            load_lds16(gB + k0,              &sh[wrt][1][wv * 512]);
            load_lds16(gB + k0 + 64 * D_DIM, &sh[wrt][1][2048 + wv * 512]);
        }
        const __bf16* shA = &sh[cur][0][0];
        const __bf16* shB = &sh[cur][1][0];
        bf16x8 af[4], bf[4];
        #pragma unroll
        for (int f = 0; f < 4; ++f) {
            af[f] = *(const bf16x8*)&shA[(wave_m + f * 16 + l15) * 32 + swz];
            bf[f] = *(const bf16x8*)&shB[(wave_n + f * 16 + l15) * 32 + swz];
        }
        #pragma unroll
        for (int fm = 0; fm < 4; ++fm)
            #pragma unroll
            for (int fn = 0; fn < 4; ++fn)
                acc[fm][fn] = __builtin_amdgcn_mfma_f32_16x16x32_bf16(
                    af[fm], bf[fn], acc[fm][fn], 0, 0, 0);
        // boundary: kt+1 must be landed; kt+2's 4 loads may stay in flight
        if (kt < NKT - 2) asm volatile("s_waitcnt vmcnt(4)" ::: "memory");
        else              asm volatile("s_waitcnt vmcnt(0)" ::: "memory");
        __builtin_amdgcn_sched_barrier(0);
        __builtin_amdgcn_s_barrier();
        cur = (cur == 2) ? 0 : cur + 1;
    }

    // epilogue: e = exp2(sim*log2(e)/t) only where c>r; row + col reductions
    int rbase = tile_m + wave_m + quad * 4;
    int cbase = tile_n + wave_n + l15;
    float colacc[4] = {0.f, 0.f, 0.f, 0.f};
    #pragma unroll
    for (int fm = 0; fm < 4; ++fm) {
        #pragma unroll
        for (int r = 0; r < 4; ++r) {
            int rg = rbase + fm * 16 + r;
            float rowacc = 0.f;
            #pragma unroll
            for (int fn = 0; fn < 4; ++fn) {
                int cg = cbase + fn * 16;
                float e = (cg > rg)
                    ? __builtin_amdgcn_exp2f(acc[fm][fn][r] * EXP_SCALE)
                    : 0.f;
                rowacc += e;
                colacc[fn] += e;
            }
            rowacc += __shfl_xor(rowacc, 1, 64);
            rowacc += __shfl_xor(rowacc, 2, 64);
            rowacc += __shfl_xor(rowacc, 4, 64);
            rowacc += __shfl_xor(rowacc, 8, 64);
            if (l15 == 0) atomicAdd(&denom[rg], rowacc);
        }
    }
    #pragma unroll
    for (int fn = 0; fn < 4; ++fn) {
        float s = colacc[fn];
        s += __shfl_xor(s, 16, 64);
        s += __shfl_xor(s, 32, 64);
        if (quad == 0) atomicAdd(&denom[cbase + fn * 16], s);
    }
}

// ---- kernel 3: loss = [sum log(denom) - (2/t) sum pos] / 2N --------------
__global__ __launch_bounds__(1024) void finalize_kernel(
    const float* __restrict__ denom, const float* __restrict__ pos,
    float* __restrict__ out)
{
    float a1 = 0.f, a2 = 0.f;
    for (int r = threadIdx.x; r < M_ROWS; r += 1024)
        a1 += __builtin_amdgcn_logf(denom[r]) * LN2;   // v_log_f32 is log2
    for (int i = threadIdx.x; i < N_BATCH; i += 1024)
        a2 += pos[i];
    #pragma unroll
    for (int m = 1; m < 64; m <<= 1) {
        a1 += __shfl_xor(a1, m, 64);
        a2 += __shfl_xor(a2, m, 64);
    }
    __shared__ float r1[16], r2[16];
    int wv = threadIdx.x >> 6;
    if ((threadIdx.x & 63) == 0) { r1[wv] = a1; r2[wv] = a2; }
    __syncthreads();
    if (threadIdx.x == 0) {
        float s1 = 0.f, s2 = 0.f;
        #pragma unroll
        for (int w = 0; w < 16; ++w) { s1 += r1[w]; s2 += r2[w]; }
        out[0] = (s1 - 2.0f * TINV * s2) / (float)M_ROWS;
    }
}

extern "C" void kernel_launch(void* const* d_in, const int* in_sizes, int n_in,
                              void* d_out, int out_size, void* d_ws, size_t ws_size,
                              hipStream_t stream)
{
    const float* emb_i = (const float*)d_in[0];
    const float* emb_j = (const float*)d_in[1];
    float* out = (float*)d_out;

    char*   ws    = (char*)d_ws;
    __bf16* zb    = (__bf16*)ws;                                   // 16 MB
    float*  denom = (float*)(ws + (size_t)M_ROWS * D_DIM * 2);     // 32 KB
    float*  pos   = denom + M_ROWS;                                // 16 KB

    hipLaunchKernelGGL(norm_pos_kernel, dim3(N_BATCH / 4), dim3(256), 0, stream,
                       emb_i, emb_j, zb, pos, denom);
    hipLaunchKernelGGL(simexp_kernel, dim3(NTRI), dim3(256), 0, stream,
                       zb, denom);
    hipLaunchKernelGGL(finalize_kernel, dim3(1), dim3(1024), 0, stream,
                       denom, pos, out);
}